// Round 5
// baseline (223.181 us; speedup 1.0000x reference)
//
#include <hip/hip_runtime.h>
#include <hip/hip_bf16.h>
#include <stdint.h>

#define Bsz   16384
#define Tt    79
#define Dd    256
#define KP    272    // padded K: 256 h + 3 x + 1 bias + 12 zero (granularity 16)
#define LROW  280    // LDS row stride in bf16 elems (560 B, 16B-aligned, 140 dw ≡ 12 mod 32)
#define NTILE 32     // batch rows per block; 512 blocks = 2 blocks/CU
#define THR   256    // 4 waves; wave wm owns m in [64*wm, 64*wm+64) as 2 32-wide tiles

typedef __attribute__((ext_vector_type(8)))  short short8;
typedef __attribute__((ext_vector_type(4)))  float float4_;
typedef __attribute__((ext_vector_type(16))) float float16_;

__device__ __forceinline__ unsigned short f2bf(float f){
  unsigned u = __float_as_uint(f);
  u += 0x7fffu + ((u >> 16) & 1u);      // RNE
  return (unsigned short)(u >> 16);
}
__device__ __forceinline__ unsigned pk2(float a, float b){
  __hip_bfloat162 h = __float22bfloat162_rn(make_float2(a, b));  // v_cvt_pk_bf16_f32
  return *(unsigned*)&h;
}

// Ut (256 x 272): Ut[m][k] = U[k][m] (k<256), W_in[k-256][m] (256..258),
//                 b_rnn[m] (k=259), 0 pad. Wdt same with W_d / b_d.
__global__ void build_tables(const float* __restrict__ W_in,
                             const float* __restrict__ U,
                             const float* __restrict__ b_rnn,
                             const float* __restrict__ W_d,
                             const float* __restrict__ b_d,
                             unsigned short* __restrict__ Ut,
                             unsigned short* __restrict__ Wdt){
  const int TBL = 256 * KP;
  int idx = blockIdx.x * 256 + threadIdx.x;
  if (idx >= 2 * TBL) return;
  int tb  = idx / TBL;
  int rem = idx - tb * TBL;
  int m = rem / KP;
  int k = rem - m * KP;
  float v = 0.f;
  if (tb == 0){
    if      (k < 256) v = U[k * 256 + m];
    else if (k < 259) v = W_in[(k - 256) * 256 + m];
    else if (k == 259) v = b_rnn[m];
  } else {
    if      (k < 256) v = W_d[k * 256 + m];
    else if (k == 259) v = b_d[m];
  }
  unsigned short o = f2bf(v);
  if (tb == 0) Ut[rem] = o; else Wdt[rem] = o;
}

// 512 blocks x 256 threads (2 blocks/CU, 2 waves/SIMD).
// h^T (32 x 272 bf16, double-buffered) in LDS. 32x32x16 MFMA:
//   A[m][k]: m=lane&31, k=8*(lane>>5)+j ; B[k][n]: n=lane&31, same k split
//   C/D: col(n)=lane&31, row(m)=(reg&3)+8*(reg>>2)+4*(lane>>5)
__global__ __launch_bounds__(THR, 2) void rnn_main(
    const float* __restrict__ x0,
    const float* __restrict__ x1,
    const float* __restrict__ x2,
    const unsigned short* __restrict__ Ut,
    const unsigned short* __restrict__ Wdt,
    float* __restrict__ out){
  __shared__ __align__(16) short hbuf[2][NTILE * LROW];

  const int tid  = threadIdx.x;
  const int lane = tid & 63;
  const int wm   = tid >> 6;    // m 64-chunk 0..3
  const int nl   = lane & 31;   // n (B/C col) and m-within-tile (A row)
  const int hi   = lane >> 5;   // k half
  const int hi8  = hi * 8;
  const int bbase = blockIdx.x * NTILE;

  // ---- zero both LDS buffers (h0 = 0, pad = 0) ----
  {
    int4* p = (int4*)&hbuf[0][0];
    const int tot = 2 * NTILE * LROW * 2 / 16;
    int4 z = make_int4(0, 0, 0, 0);
    for (int i = tid; i < tot; i += THR) p[i] = z;
  }
  __syncthreads();

  // bias row k=259 = 1.0 bf16 in both buffers (never overwritten)
  if (tid < NTILE){
    hbuf[0][tid * LROW + 259] = (short)0x3F80;
    hbuf[1][tid * LROW + 259] = (short)0x3F80;
  }

  // stager: 8 lanes per wave, each owns one of the block's 32 batch rows
  const bool stager = (lane < 8);
  const int  sn  = wm * 8 + (lane & 7);
  const int  sgb = bbase + sn;
  if (stager){
    int tr = Tt - 1;
    float a = x0[sgb * Tt + tr];
    float b = x1[sgb * Tt + tr];
    float c = x2[sgb * Tt + tr];
    *(unsigned*)&hbuf[0][sn * LROW + 256] = pk2(a, b);
    hbuf[0][sn * LROW + 258] = (short)f2bf(c);
  }

  // ---- A fragments: 2 m-tiles x 17 k-tiles = 34 short8 (136 dw) ----
  short8 afr[2][17];
  #pragma unroll
  for (int mt = 0; mt < 2; ++mt){
    const unsigned short* p = Ut + (wm * 64 + mt * 32 + nl) * KP + hi8;
    #pragma unroll
    for (int kt = 0; kt < 17; ++kt){
      afr[mt][kt] = *(const short8*)(p + kt * 16);
    }
  }

  __syncthreads();

  const float16_ zz16 = {0.f,0.f,0.f,0.f,0.f,0.f,0.f,0.f,
                         0.f,0.f,0.f,0.f,0.f,0.f,0.f,0.f};

  auto step = [&](const short* __restrict__ hb, short* __restrict__ hw, int t){
    // prefetch x(t+1) (hidden under the K-loop)
    float xa = 0.f, xb = 0.f, xc = 0.f;
    const bool pf = stager && (t < Tt - 1);
    if (pf){
      int tr = Tt - 2 - t;
      xa = x0[sgb * Tt + tr];
      xb = x1[sgb * Tt + tr];
      xc = x2[sgb * Tt + tr];
    }

    float16_ a0, a1;
    #pragma unroll
    for (int kt = 0; kt < 17; ++kt){
      short8 b = *(const short8*)&hb[nl * LROW + kt * 16 + hi8];
      if (kt == 0){
        a0 = __builtin_amdgcn_mfma_f32_32x32x16_bf16(afr[0][0], b, zz16, 0, 0, 0);
        a1 = __builtin_amdgcn_mfma_f32_32x32x16_bf16(afr[1][0], b, zz16, 0, 0, 0);
      } else {
        a0 = __builtin_amdgcn_mfma_f32_32x32x16_bf16(afr[0][kt], b, a0, 0, 0, 0);
        a1 = __builtin_amdgcn_mfma_f32_32x32x16_bf16(afr[1][kt], b, a1, 0, 0, 0);
      }
    }

    // relu + pack + write h(t+1); reg group g holds rows m = 8g + 4hi + 0..3
    #pragma unroll
    for (int g = 0; g < 4; ++g){
      uint2 w;
      w.x = pk2(fmaxf(a0[4*g+0], 0.f), fmaxf(a0[4*g+1], 0.f));
      w.y = pk2(fmaxf(a0[4*g+2], 0.f), fmaxf(a0[4*g+3], 0.f));
      *(uint2*)&hw[nl * LROW + wm * 64 +      8 * g + 4 * hi] = w;
      w.x = pk2(fmaxf(a1[4*g+0], 0.f), fmaxf(a1[4*g+1], 0.f));
      w.y = pk2(fmaxf(a1[4*g+2], 0.f), fmaxf(a1[4*g+3], 0.f));
      *(uint2*)&hw[nl * LROW + wm * 64 + 32 + 8 * g + 4 * hi] = w;
    }
    if (pf){
      *(unsigned*)&hw[sn * LROW + 256] = pk2(xa, xb);
      hw[sn * LROW + 258] = (short)f2bf(xc);
    }
    __syncthreads();
  };

  // ---- 79 steps: explicit ping-pong (loop-invariant LDS bases) ----
  #pragma unroll 1
  for (int t = 0; t < Tt - 1; t += 2){
    step(&hbuf[0][0], &hbuf[1][0], t);
    step(&hbuf[1][0], &hbuf[0][0], t + 1);
  }
  step(&hbuf[0][0], &hbuf[1][0], Tt - 1);   // t = 78 (even), final h -> buf 1

  // ---- epilogue: out^T = W_d^T h^T + b_d ----
  const short* hb = &hbuf[1][0];
  float16_ o0, o1;
  #pragma unroll
  for (int kt = 0; kt < 17; ++kt){
    short8 w0 = *(const short8*)(Wdt + (wm * 64 +      nl) * KP + kt * 16 + hi8);
    short8 w1 = *(const short8*)(Wdt + (wm * 64 + 32 + nl) * KP + kt * 16 + hi8);
    short8 b  = *(const short8*)&hb[nl * LROW + kt * 16 + hi8];
    if (kt == 0){
      o0 = __builtin_amdgcn_mfma_f32_32x32x16_bf16(w0, b, zz16, 0, 0, 0);
      o1 = __builtin_amdgcn_mfma_f32_32x32x16_bf16(w1, b, zz16, 0, 0, 0);
    } else {
      o0 = __builtin_amdgcn_mfma_f32_32x32x16_bf16(w0, b, o0, 0, 0, 0);
      o1 = __builtin_amdgcn_mfma_f32_32x32x16_bf16(w1, b, o1, 0, 0, 0);
    }
  }
  #pragma unroll
  for (int g = 0; g < 4; ++g){
    int m0 = wm * 64 + 8 * g + 4 * hi;
    float4_ v0 = {o0[4*g+0], o0[4*g+1], o0[4*g+2], o0[4*g+3]};
    float4_ v1 = {o1[4*g+0], o1[4*g+1], o1[4*g+2], o1[4*g+3]};
    *(float4_*)&out[(bbase + nl) * Dd + m0]      = v0;
    *(float4_*)&out[(bbase + nl) * Dd + m0 + 32] = v1;
  }
}

extern "C" void kernel_launch(void* const* d_in, const int* in_sizes, int n_in,
                              void* d_out, int out_size, void* d_ws, size_t ws_size,
                              hipStream_t stream){
  const float* x0    = (const float*)d_in[0];
  const float* x1    = (const float*)d_in[1];
  const float* x2    = (const float*)d_in[2];
  const float* W_in  = (const float*)d_in[3];
  const float* U     = (const float*)d_in[4];
  const float* b_rnn = (const float*)d_in[5];
  const float* W_d   = (const float*)d_in[6];
  const float* b_d   = (const float*)d_in[7];

  unsigned short* Ut  = (unsigned short*)d_ws;
  unsigned short* Wdt = Ut + 256 * KP;
  float* out = (float*)d_out;

  build_tables<<<(2 * 256 * KP + 255) / 256, 256, 0, stream>>>(W_in, U, b_rnn, W_d, b_d, Ut, Wdt);
  rnn_main<<<Bsz / NTILE, THR, 0, stream>>>(x0, x1, x2, Ut, Wdt, out);
}